// Round 2
// baseline (442.395 us; speedup 1.0000x reference)
//
#include <hip/hip_runtime.h>
#include <hip/hip_bf16.h>
#include <stdint.h>

// MoE gate: logits = r @ W^T + b ; soft = softmax(logits) ; hard = top8-renorm
// r: (32768, 2048) fp32, W: (64, 2048) fp32, b: (64,) fp32
// d_out: [hard (32768*64) | soft (32768*64)] fp32
//
// Precision: exact bf16^3 split of both operands, 6 MFMA terms in 3 scale-
// class accumulators (verified: absmax 0.00195 vs 0.01625 thr).
//
// Round-5 theory: round-4 was still barrier-bound (per-k-step __syncthreads
// drains vmcnt(0)) and its LDS fragment reads were 8-way bank-conflicted
// (6.36M conflicts). Split-W (768 KB) is L2-resident by construction, so LDS
// staging buys nothing: this round reads B fragments DIRECTLY from the
// pre-permuted global image P (each fragment = 64 lanes x 16 B over one
// aligned 1 KB block -> fully coalesced, L2-hit). Zero barriers in the
// K-loop; waves run independently. K-quartered waves (4 waves/block = 4
// quarters, 16 rows/block, grid 2048), one barrier before quarter-reduce +
// fused softmax/top-8. launch_bounds(256,4) -> 16 waves/CU; HBM r-stream
// (268 MB, 43 us floor) should now be the limiter.

#define D_DIM 2048
#define E_DIM 64
#define B_DIM 32768
#define TOPK 8
#define NK 16   // k-steps per quarter (32 k each)

typedef __bf16 bf16x8 __attribute__((ext_vector_type(8)));
typedef float f32x4 __attribute__((ext_vector_type(4)));

// ---- prep: W fp32 -> per-kstep fragment image ----
// P[ks][split][2048 bf16] = 12 KB per kstep. Element (s, u*8+j) = split_s of
// W[e = u>>2][ks*32 + (u&3)*8 + j]. Fragment (s,n) of kstep ks occupies the
// contiguous aligned 1 KB at P + ks*6144 + s*2048 + n*512; within it, lane
// (quad,lrow) reads 16 B at quad*16 + lrow*64 -> expert n*16+lrow, k-chunk
// quad*8 .. +8, matching the mfma_f32_16x16x32_bf16 B-fragment layout.
__global__ __launch_bounds__(256) void w_prep(const float* __restrict__ W,
                                              __bf16* __restrict__ P) {
    const int K = blockIdx.x;    // kstep 0..63
    const int u = threadIdx.x;   // slot 0..255
    const float* src = W + (size_t)(u >> 2) * D_DIM + K * 32 + (u & 3) * 8;
    __bf16* dst = P + (size_t)K * 6144 + u * 8;
    bf16x8 o1, o2, o3;
    #pragma unroll
    for (int j = 0; j < 8; ++j) {
        float x  = src[j];
        __bf16 h1 = (__bf16)x;
        float r1 = x - (float)h1;          // exact
        __bf16 h2 = (__bf16)r1;
        float r2 = r1 - (float)h2;         // exact
        o1[j] = h1; o2[j] = h2; o3[j] = (__bf16)r2;
    }
    *(bf16x8*)(dst)        = o1;
    *(bf16x8*)(dst + 2048) = o2;
    *(bf16x8*)(dst + 4096) = o3;
}

// ---- main: 6-term split GEMM + fused softmax/top-8, barrier-free K-loop ----
// Block = 256 thr = 4 waves; wave wv = K-quarter q, owns 16 rows x 64 experts
// x 512 k. Grid = 2048 blocks (16 rows each).
__global__ __launch_bounds__(256, 4) void moe_gate(const float* __restrict__ r,
                                                   const __bf16* __restrict__ P,
                                                   const float* __restrict__ bias,
                                                   float* __restrict__ out) {
    __shared__ float lg[4][16][E_DIM + 1];   // per-quarter partials, 16.6 KB

    const int t    = threadIdx.x;
    const int wv   = t >> 6;     // K quarter
    const int lane = t & 63;
    const int lrow = lane & 15;
    const int quad = lane >> 4;
    const int row0 = blockIdx.x * 16;

    // B source: this quarter's k-steps, this lane's 16 B within each fragment
    const __bf16* Pq = P + (size_t)wv * NK * 6144 + quad * 8 + lrow * 32;
    // A source: row lrow, this quarter's k range, quad's 8-float chunk
    const float* ra = r + (size_t)(row0 + lrow) * D_DIM + wv * 512 + quad * 8;

    f32x4 accM[4] = {};  // h1*g1              (~1)
    f32x4 accD[4] = {};  // h1*g2 + h2*g1      (~2^-8)
    f32x4 accL[4] = {};  // h1*g3+h2*g2+h3*g1  (~2^-16)

    float4 a0 = *(const float4*)(ra);
    float4 a1 = *(const float4*)(ra + 4);

    #pragma unroll 2
    for (int ks = 0; ks < NK; ++ks) {
        const int kn = ks + 1;
        // keep the HBM A-stream ahead: issue next-step loads first
        float4 na0 = a0, na1 = a1;
        if (kn < NK) {
            na0 = *(const float4*)(ra + kn * 32);
            na1 = *(const float4*)(ra + kn * 32 + 4);
        }

        // 12 B fragments direct from L2 (each: coalesced 1 KB, no LDS)
        const __bf16* bb = Pq + (size_t)ks * 6144;
        bf16x8 B[3][4];
        #pragma unroll
        for (int s = 0; s < 3; ++s)
            #pragma unroll
            for (int n = 0; n < 4; ++n)
                B[s][n] = *(const bf16x8*)(bb + s * 2048 + n * 512);

        // split current A (independent of B loads -> hides their latency)
        float av[8] = {a0.x, a0.y, a0.z, a0.w, a1.x, a1.y, a1.z, a1.w};
        bf16x8 A1, A2, A3;
        #pragma unroll
        for (int j = 0; j < 8; ++j) {
            float x  = av[j];
            __bf16 h1 = (__bf16)x;
            float r1 = x - (float)h1;
            __bf16 h2 = (__bf16)r1;
            float r2 = r1 - (float)h2;
            A1[j] = h1; A2[j] = h2; A3[j] = (__bf16)r2;
        }

        #pragma unroll
        for (int n = 0; n < 4; ++n) {
            accM[n] = __builtin_amdgcn_mfma_f32_16x16x32_bf16(A1, B[0][n], accM[n], 0, 0, 0);
            accD[n] = __builtin_amdgcn_mfma_f32_16x16x32_bf16(A1, B[1][n], accD[n], 0, 0, 0);
            accD[n] = __builtin_amdgcn_mfma_f32_16x16x32_bf16(A2, B[0][n], accD[n], 0, 0, 0);
            accL[n] = __builtin_amdgcn_mfma_f32_16x16x32_bf16(A1, B[2][n], accL[n], 0, 0, 0);
            accL[n] = __builtin_amdgcn_mfma_f32_16x16x32_bf16(A2, B[1][n], accL[n], 0, 0, 0);
            accL[n] = __builtin_amdgcn_mfma_f32_16x16x32_bf16(A3, B[0][n], accL[n], 0, 0, 0);
        }

        a0 = na0; a1 = na1;
    }

    // C/D layout: col = lane&15, row = quad*4 + reg. Combine small-first,
    // one partial per K-quarter.
    #pragma unroll
    for (int n = 0; n < 4; ++n) {
        int col = n * 16 + lrow;
        #pragma unroll
        for (int i = 0; i < 4; ++i)
            lg[wv][quad * 4 + i][col] = accM[n][i] + (accD[n][i] + accL[n][i]);
    }
    __syncthreads();   // the ONLY block-wide barrier

    // quarter-reduce + softmax + top-8; wave per row, lane = expert. T == 1.
    const float bcol = bias[lane];
    for (int rr = wv; rr < 16; rr += 4) {
        float logit = ((lg[0][rr][lane] + lg[1][rr][lane]) +
                       (lg[2][rr][lane] + lg[3][rr][lane])) + bcol;
        float mx = logit;
        #pragma unroll
        for (int s = 32; s >= 1; s >>= 1) mx = fmaxf(mx, __shfl_xor(mx, s));
        float ex = expf(logit - mx);
        float sm = ex;
        #pragma unroll
        for (int s = 32; s >= 1; s >>= 1) sm += __shfl_xor(sm, s);
        float soft = ex / sm;

        // top-8 on soft (monotone in logit); lowest-index tie-break = lax.top_k
        bool  sel    = false;
        float topsum = 0.0f;
        #pragma unroll
        for (int it = 0; it < TOPK; ++it) {
            float cand = sel ? -1.0f : soft;  // soft > 0 always
            float cm = cand;
            #pragma unroll
            for (int s = 32; s >= 1; s >>= 1) cm = fmaxf(cm, __shfl_xor(cm, s));
            unsigned long long ball = __ballot(cand == cm);
            int leader = __ffsll(ball) - 1;
            if (lane == leader) sel = true;
            topsum += cm;
        }
        float hard = sel ? soft / (topsum + 1e-9f) : 0.0f;

        size_t orow = (size_t)(row0 + rr) * E_DIM + lane;
        out[orow] = hard;
        out[(size_t)B_DIM * E_DIM + orow] = soft;
    }
}

extern "C" void kernel_launch(void* const* d_in, const int* in_sizes, int n_in,
                              void* d_out, int out_size, void* d_ws, size_t ws_size,
                              hipStream_t stream) {
    const float* r = (const float*)d_in[0];
    const float* W = (const float*)d_in[1];
    const float* b = (const float*)d_in[2];
    float* out = (float*)d_out;
    __bf16* P = (__bf16*)d_ws;   // 64 ksteps * 12 KB = 768 KB of ws

    w_prep<<<64, 256, 0, stream>>>(W, P);
    moe_gate<<<2048, 256, 0, stream>>>(r, P, b, out);
}